// Round 7
// baseline (238.731 us; speedup 1.0000x reference)
//
#include <hip/hip_runtime.h>
#include <math.h>

// Problem constants
constexpr int Bc = 2;
constexpr int Sc = 2048;
constexpr int Dc = 1024;
constexpr int Hc = 16;
constexpr int HDc = 64;

// Q pre-scale: attention 1/sqrt(64) folded with log2(e) for exp2-domain softmax
constexpr float QSC = 0.125f * 1.4426950408889634f;

typedef __attribute__((ext_vector_type(8))) short bf16x8;
typedef __attribute__((ext_vector_type(4))) float f32x4;
typedef __attribute__((ext_vector_type(4))) unsigned short us4;
typedef __attribute__((ext_vector_type(2))) unsigned int u32x2;
typedef __attribute__((ext_vector_type(4))) unsigned int u32x4;

// fp32 -> bf16 round-to-nearest-even (returns low 16 bits)
__device__ __forceinline__ unsigned f2bf(float x) {
    unsigned u = __float_as_uint(x);
    return (u + 0x7FFFu + ((u >> 16) & 1u)) >> 16;
}

__device__ __forceinline__ void split2(float x, unsigned short& h, unsigned short& l) {
    unsigned hh = f2bf(x);
    h = (unsigned short)hh;
    l = (unsigned short)f2bf(x - __uint_as_float(hh << 16));
}

// gfx950 cross-lane half-swaps: a=vdst, b=src; both updated.
#if __has_builtin(__builtin_amdgcn_permlane32_swap)
__device__ __forceinline__ void plswap32(unsigned& a, unsigned& b) {
    u32x2 r = __builtin_amdgcn_permlane32_swap(a, b, false, false);
    a = r.x; b = r.y;
}
#else
__device__ __forceinline__ void plswap32(unsigned& a, unsigned& b) {
    asm volatile("v_permlane32_swap_b32 %0, %1" : "+v"(a), "+v"(b));
}
#endif
#if __has_builtin(__builtin_amdgcn_permlane16_swap)
__device__ __forceinline__ void plswap16(unsigned& a, unsigned& b) {
    u32x2 r = __builtin_amdgcn_permlane16_swap(a, b, false, false);
    a = r.x; b = r.y;
}
#else
__device__ __forceinline__ void plswap16(unsigned& a, unsigned& b) {
    asm volatile("v_permlane16_swap_b32 %0, %1" : "+v"(a), "+v"(b));
}
#endif

// exp2 of 4 S-values, packed (truncating) into two bf16-pair words:
// w0 = {bf16(s0) lo, bf16(s1) hi}, w1 = {bf16(s2) lo, bf16(s3) hi}
__device__ __forceinline__ void exppack(const f32x4& sv, unsigned& w0, unsigned& w1) {
    unsigned u0 = __float_as_uint(__builtin_amdgcn_exp2f(sv[0]));
    unsigned u1 = __float_as_uint(__builtin_amdgcn_exp2f(sv[1]));
    unsigned u2 = __float_as_uint(__builtin_amdgcn_exp2f(sv[2]));
    unsigned u3 = __float_as_uint(__builtin_amdgcn_exp2f(sv[3]));
    w0 = __builtin_amdgcn_perm(u1, u0, 0x07060302u);
    w1 = __builtin_amdgcn_perm(u3, u2, 0x07060302u);
}

// ---------------------------------------------------------------------------
// RoPE cos/sin table: [S][32] each, double precision angles.
// ---------------------------------------------------------------------------
__global__ void rope_table(float* __restrict__ ct, float* __restrict__ st_) {
    int id = blockIdx.x * 256 + threadIdx.x;
    int s = id >> 5;
    int i = id & 31;
    double invf = pow(10000.0, -(double)i / 32.0);
    double ang = (double)s * invf;
    ct[id] = (float)cos(ang);
    st_[id] = (float)sin(ang);
}

// ---------------------------------------------------------------------------
// Convert: x -> bf16 hi; Wq/Wk/Wv -> hi; Wo -> hi + lo.
// ---------------------------------------------------------------------------
__global__ void split_xw(const float* __restrict__ x,
                         const float* __restrict__ Wq, const float* __restrict__ Wk,
                         const float* __restrict__ Wv, const float* __restrict__ Wo,
                         unsigned short* __restrict__ xh,
                         unsigned short* __restrict__ whAll, unsigned short* __restrict__ wlAll) {
    int y = blockIdx.y;
    const float* src;
    unsigned short* h;
    unsigned short* l = nullptr;
    int n;
    if (y == 0) { src = x; h = xh; n = 1 << 22; }
    else {
        src = (y == 1) ? Wq : (y == 2) ? Wk : (y == 3) ? Wv : Wo;
        h = whAll + (size_t)(y - 1) * (1 << 20);
        if (y == 4) l = wlAll + (size_t)3 * (1 << 20);
        n = 1 << 20;
    }
    int i = (blockIdx.x * 256 + threadIdx.x) * 4;
    if (i >= n) return;
    float4 v = *(const float4*)(src + i);
    us4 hh;
    ((unsigned short*)&hh)[0] = (unsigned short)f2bf(v.x);
    ((unsigned short*)&hh)[1] = (unsigned short)f2bf(v.y);
    ((unsigned short*)&hh)[2] = (unsigned short)f2bf(v.z);
    ((unsigned short*)&hh)[3] = (unsigned short)f2bf(v.w);
    *(us4*)(h + i) = hh;
    if (l) {
        us4 ll;
        const float* vp = (const float*)&v;
#pragma unroll
        for (int e = 0; e < 4; e++) {
            unsigned short hi = ((unsigned short*)&hh)[e];
            ((unsigned short*)&ll)[e] =
                (unsigned short)f2bf(vp[e] - __uint_as_float((unsigned)hi << 16));
        }
        *(us4*)(l + i) = ll;
    }
}

// ---------------------------------------------------------------------------
// QKV GEMM, bf16 1-product, 128x128 tile, BK=32, dbuf, 8 waves (512 thr,
// per-wave 32x64 subtile) — round-6 proven: 60us, occ 58%. UNTOUCHED.
// Epilogues: z=0 Q (RoPE+QSC row-major), z=1 K (RoPE, [T][kb][tok][8] cells),
//            z=2 V (V^T cells [T][kk(2)][qd(4)][d(64)][tok8] — native K=32
//                   A-operand layout for attention PV)
// ---------------------------------------------------------------------------
__global__ __launch_bounds__(512, 4) void gemm_qkv(
    const unsigned short* __restrict__ Ah,
    const unsigned short* __restrict__ whAll,
    unsigned short* __restrict__ Qh,
    unsigned short* __restrict__ Kh,
    unsigned short* __restrict__ Vh,
    const float* __restrict__ ct, const float* __restrict__ st_) {
    constexpr int K = 1024;
    // [buf2][kcell4][row128][8]
    __shared__ __align__(16) unsigned short As[2 * 4096], Bs[2 * 4096];

    const int z = blockIdx.z;
    const unsigned short* Wh = whAll + (size_t)z * (1 << 20);

    const int t = threadIdx.x;
    const int lane = t & 63;
    const int wave = t >> 6;               // 0..7
    const int l = lane & 15;
    const int quad = lane >> 4;
    const int wr = wave >> 1;              // 0..3: 32-row strip
    const int wc = wave & 1;               // 0..1: 64-col strip (= head)
    const int m0 = blockIdx.x * 128;
    const int n0 = blockIdx.y * 128;

    // staging: thread t owns row (t&127), kcell (t>>7) of both A and B.
    const int arow = t & 127, akc = t >> 7;
    const unsigned short* gA = Ah + (size_t)(m0 + arow) * K + akc * 8;
    const unsigned short* gB = Wh + (size_t)(n0 + arow) * K + akc * 8;

    f32x4 acc[2][4];
#pragma unroll
    for (int i = 0; i < 2; i++)
#pragma unroll
        for (int j = 0; j < 4; j++) acc[i][j] = (f32x4){0.f, 0.f, 0.f, 0.f};

    __builtin_amdgcn_global_load_lds(
        (const __attribute__((address_space(1))) unsigned int*)gA,
        (__attribute__((address_space(3))) unsigned int*)(As + t * 8), 16, 0, 0);
    __builtin_amdgcn_global_load_lds(
        (const __attribute__((address_space(1))) unsigned int*)gB,
        (__attribute__((address_space(3))) unsigned int*)(Bs + t * 8), 16, 0, 0);

    for (int it = 0; it < 32; ++it) {
        __syncthreads();
        if (it + 1 < 32) {
            const int koff = (it + 1) * 32;
            const int bo = ((it + 1) & 1) * 4096;
            __builtin_amdgcn_global_load_lds(
                (const __attribute__((address_space(1))) unsigned int*)(gA + koff),
                (__attribute__((address_space(3))) unsigned int*)(As + bo + t * 8), 16, 0, 0);
            __builtin_amdgcn_global_load_lds(
                (const __attribute__((address_space(1))) unsigned int*)(gB + koff),
                (__attribute__((address_space(3))) unsigned int*)(Bs + bo + t * 8), 16, 0, 0);
        }
        const unsigned short* a = As + (it & 1) * 4096;
        const unsigned short* bb = Bs + (it & 1) * 4096;
        bf16x8 ah[2], bh[4];
#pragma unroll
        for (int i = 0; i < 2; i++)
            ah[i] = *(const bf16x8*)&a[(quad * 128 + wr * 32 + i * 16 + l) * 8];
#pragma unroll
        for (int j = 0; j < 4; j++)
            bh[j] = *(const bf16x8*)&bb[(quad * 128 + wc * 64 + j * 16 + l) * 8];
#pragma unroll
        for (int i = 0; i < 2; i++)
#pragma unroll
            for (int j = 0; j < 4; j++)
                acc[i][j] = __builtin_amdgcn_mfma_f32_16x16x32_bf16(ah[i], bh[j], acc[i][j], 0, 0, 0);
    }

    // ---- fused epilogue ----
    const int hcol = blockIdx.y * 2 + wc;   // head index 0..15
    if (z == 2) {
        // V^T cells, K=32 A-operand layout:
        //   off = ((kk*4 + qd)*64 + d)*8 + tj, tok64 = kk*32 + qd*8 + tj
        // acc[i][jj][r]: tok64 = ii*16 + quad*4 + r with ii = (2*wr+i)&3
#pragma unroll
        for (int i = 0; i < 2; i++) {
            int m_base = m0 + wr * 32 + i * 16 + quad * 4;
            int bbk = m_base >> 11;
            int T = (m_base & (Sc - 1)) >> 6;
            int ii = (2 * wr + i) & 3;
            int kk = ii >> 1;
            int qd = ((ii & 1) << 1) | (quad >> 1);
            int tj = (quad & 1) * 4;
            size_t tilebase = (((size_t)(bbk * Hc + hcol)) * 32 + T) * 4096;
#pragma unroll
            for (int jj = 0; jj < 4; jj++) {
                int d = jj * 16 + l;
                size_t off = tilebase + (size_t)(((kk * 4 + qd) * 64 + d) * 8 + tj);
                us4 v4;
#pragma unroll
                for (int r = 0; r < 4; r++)
                    ((unsigned short*)&v4)[r] = (unsigned short)f2bf(acc[i][jj][r]);
                *(us4*)(Vh + off) = v4;
            }
        }
    } else {
#pragma unroll
        for (int i = 0; i < 2; i++)
#pragma unroll
            for (int r = 0; r < 4; r++) {
                int m = m0 + wr * 32 + i * 16 + quad * 4 + r;
                int bbk = m >> 11, s = m & (Sc - 1);
#pragma unroll
                for (int jp = 0; jp < 2; jp++) {
                    int d = jp * 16 + l;                       // 0..31
                    float cs = ct[s * 32 + d];
                    float sn = st_[s * 32 + d];
                    float x0 = acc[i][jp][r];
                    float x1 = acc[i][jp + 2][r];
                    float y0 = x0 * cs - x1 * sn;
                    float y1 = x1 * cs + x0 * sn;
                    if (z == 0) {
                        size_t rowb = (((size_t)(bbk * Hc + hcol)) * Sc + s) * HDc;
                        Qh[rowb + d]      = (unsigned short)f2bf(y0 * QSC);
                        Qh[rowb + d + 32] = (unsigned short)f2bf(y1 * QSC);
                    } else {
                        int T = s >> 6, tok = s & 63;
                        size_t tb = (((size_t)(bbk * Hc + hcol)) * 32 + T) * 8;
                        size_t off0 = ((tb + (d >> 3)) * 64 + tok) * 8 + (d & 7);
                        size_t off1 = ((tb + (d >> 3) + 4) * 64 + tok) * 8 + (d & 7);
                        Kh[off0] = (unsigned short)f2bf(y0);
                        Kh[off1] = (unsigned short)f2bf(y1);
                    }
                }
            }
    }
}

// ---------------------------------------------------------------------------
// MFMA flash attention v10: all-K=32 MFMA, 256 q/block (8 waves x 2 bands),
// grid 256 = 1 block/CU. K/V staging per CU per kt halved again vs v9 (16 KB
// per 256 q). Triple-buffered K/V + per-wave counted vmcnt(2) BEFORE the raw
// s_barrier (attn9-proven race-free shape): DMA queue never drains.
// XCD-clustered: the 8 q-tiles of one (b,h) share an XCD slot (K/V L2-local).
// ---------------------------------------------------------------------------
__global__ __launch_bounds__(512) void attn10(
    const unsigned short* __restrict__ Qh,
    const unsigned short* __restrict__ Kh,
    const unsigned short* __restrict__ Vh,
    unsigned short* __restrict__ AOh, unsigned short* __restrict__ AOl) {
    __shared__ __align__(16) unsigned short KsH[3 * 4096], VtH[3 * 4096];

    const int t = threadIdx.x;
    const int lane = t & 63;
    const int wave = t >> 6;               // 0..7
    const int l = lane & 15;
    const int quad = lane >> 4;
    const int id = blockIdx.x;             // 0..255
    const int bh = (id & 7) * 4 + (id >> 6);   // XCD-clustered (4 bh / XCD slot)
    const int qt = (id >> 3) & 7;
    const int q0 = qt * 256;
    const int b = bh >> 4;
    const int hh = bh & 15;

    const bf16x8 ONES8 = {(short)0x3F80, (short)0x3F80, (short)0x3F80, (short)0x3F80,
                          (short)0x3F80, (short)0x3F80, (short)0x3F80, (short)0x3F80};

    // Q fragments (B operand: n=q=lane&15, k=d=quad*8+j); band bnd -> rows
    // q0 + wave*32 + bnd*16 + l
    bf16x8 qf[2][2];
#pragma unroll
    for (int bnd = 0; bnd < 2; bnd++) {
        size_t rowb = ((size_t)bh * Sc + q0 + wave * 32 + bnd * 16 + l) * HDc;
#pragma unroll
        for (int ks = 0; ks < 2; ks++)
            qf[bnd][ks] = *(const bf16x8*)(Qh + rowb + ks * 32 + quad * 8);
    }

    f32x4 o[2][4], lac[2];
#pragma unroll
    for (int bnd = 0; bnd < 2; bnd++) {
        lac[bnd] = (f32x4){0.f, 0.f, 0.f, 0.f};
#pragma unroll
        for (int i = 0; i < 4; i++) o[bnd][i] = (f32x4){0.f, 0.f, 0.f, 0.f};
    }

    // staging: 16 chunks of 512 elems per kt (K: 0-7, V: 8-15); wave w owns
    // chunks w*2, w*2+1 (waves 0-3 -> K, waves 4-7 -> V). LDS dst uniform.
    const int tensor = wave >> 2;          // 0 = K, 1 = V
    const int coff0 = (wave * 2) & 7;      // 0,2,4,6
    unsigned short* larr = tensor ? VtH : KsH;
    const unsigned short* gT =
        (tensor ? Vh : Kh) + (size_t)bh * Sc * HDc + coff0 * 512 + lane * 8;

    // prologue: kt=0 into buffer 0
#pragma unroll
    for (int q = 0; q < 2; q++)
        __builtin_amdgcn_global_load_lds(
            (const __attribute__((address_space(1))) unsigned int*)(gT + q * 512),
            (__attribute__((address_space(3))) unsigned int*)(larr + coff0 * 512 + q * 512),
            16, 0, 0);

    int bc = 0;   // kt % 3
    for (int kt = 0; kt < 32; kt++) {
        if (kt + 1 < 32) {
            int nb = bc + 1; if (nb == 3) nb = 0;     // (kt+1) % 3
            const unsigned short* g = gT + (size_t)(kt + 1) * 4096;
            unsigned short* dst = larr + nb * 4096 + coff0 * 512;
#pragma unroll
            for (int q = 0; q < 2; q++)
                __builtin_amdgcn_global_load_lds(
                    (const __attribute__((address_space(1))) unsigned int*)(g + q * 512),
                    (__attribute__((address_space(3))) unsigned int*)(dst + q * 512),
                    16, 0, 0);
            asm volatile("s_waitcnt vmcnt(2)" ::: "memory");   // own kt-loads landed
        } else {
            asm volatile("s_waitcnt vmcnt(0)" ::: "memory");
        }
        __builtin_amdgcn_s_barrier();                          // all waves' kt-loads landed
        const unsigned short* Kbuf = KsH + bc * 4096;
        const unsigned short* Vbuf = VtH + bc * 4096;

        // ---- S^T = K @ Q^T: A=K frag (m=tok), B=Q frag (n=q) ----
        f32x4 s[2][4];
#pragma unroll
        for (int bnd = 0; bnd < 2; bnd++)
#pragma unroll
            for (int tt = 0; tt < 4; tt++) s[bnd][tt] = (f32x4){0.f, 0.f, 0.f, 0.f};
        __builtin_amdgcn_s_setprio(1);
#pragma unroll
        for (int ks = 0; ks < 2; ks++)
#pragma unroll
            for (int tt = 0; tt < 4; tt++) {
                bf16x8 kf = *(const bf16x8*)&Kbuf[((ks * 4 + quad) * 64 + tt * 16 + l) * 8];
                s[0][tt] = __builtin_amdgcn_mfma_f32_16x16x32_bf16(kf, qf[0][ks], s[0][tt], 0, 0, 0);
                s[1][tt] = __builtin_amdgcn_mfma_f32_16x16x32_bf16(kf, qf[1][ks], s[1][tt], 0, 0, 0);
            }
        __builtin_amdgcn_s_setprio(0);

        // ---- P^T = exp2(S^T), packed + permlane-transposed into K=32
        //      B-operand fragments (tokens quad*8+j contiguous per lane) ----
        bf16x8 pf[2][2];
#pragma unroll
        for (int bnd = 0; bnd < 2; bnd++)
#pragma unroll
            for (int ttp = 0; ttp < 2; ttp++) {
                unsigned A0, A1, B0, B1;
                exppack(s[bnd][2 * ttp], A0, A1);       // tokens ttp*32 + quad*4 + {0..3}
                exppack(s[bnd][2 * ttp + 1], B0, B1);   // tokens ttp*32 + 16 + quad*4 + {0..3}
                plswap32(A0, B0);
                plswap16(A0, B0);   // A0 -> frag word0, B0 -> frag word2
                plswap32(A1, B1);
                plswap16(A1, B1);   // A1 -> frag word1, B1 -> frag word3
                u32x4 fw = {A0, A1, B0, B1};
                bf16x8 p8 = __builtin_bit_cast(bf16x8, fw);
                pf[bnd][ttp] = p8;
                lac[bnd] = __builtin_amdgcn_mfma_f32_16x16x32_bf16(ONES8, p8, lac[bnd], 0, 0, 0);
            }

        // ---- O^T += V^T @ P^T (K=32; V frags shared across bands) ----
        __builtin_amdgcn_s_setprio(1);
#pragma unroll
        for (int kk = 0; kk < 2; kk++)
#pragma unroll
            for (int dd = 0; dd < 4; dd++) {
                bf16x8 vf = *(const bf16x8*)
                    &Vbuf[(size_t)((kk * 4 + quad) * 64 + dd * 16 + l) * 8];
                o[0][dd] = __builtin_amdgcn_mfma_f32_16x16x32_bf16(vf, pf[0][kk], o[0][dd], 0, 0, 0);
                o[1][dd] = __builtin_amdgcn_mfma_f32_16x16x32_bf16(vf, pf[1][kk], o[1][dd], 0, 0, 0);
            }
        __builtin_amdgcn_s_setprio(0);
        if (++bc == 3) bc = 0;
    }

    // ---- epilogue: O^T frag: col q = lane&15, row d = dd*16 + quad*4 + r ----
#pragma unroll
    for (int bnd = 0; bnd < 2; bnd++) {
        float inv = 1.f / lac[bnd][0];   // all 4 regs equal (ONES-A rows identical)
        int q = q0 + wave * 32 + bnd * 16 + l;
        size_t rowb = ((size_t)b * Sc + q) * Dc + hh * HDc + quad * 4;
#pragma unroll
        for (int dd = 0; dd < 4; dd++) {
            us4 h4, l4;
#pragma unroll
            for (int r = 0; r < 4; r++)
                split2(o[bnd][dd][r] * inv,
                       ((unsigned short*)&h4)[r], ((unsigned short*)&l4)[r]);
            *(us4*)(AOh + rowb + dd * 16) = h4;
            *(us4*)(AOl + rowb + dd * 16) = l4;
        }
    }
}

// ---------------------------------------------------------------------------
// Output projection GEMM (MFMA split-bf16 3-product), 128x128 tile, 8 waves.
// TRIPLE-buffered (96 KB) + counted vmcnt(4) before raw s_barrier — at
// 1 block/CU the __syncthreads drain was fully exposed; now it never drains.
// ---------------------------------------------------------------------------
__global__ __launch_bounds__(512, 2) void gemm_out(
    const unsigned short* __restrict__ Ah, const unsigned short* __restrict__ Al,
    const unsigned short* __restrict__ Wh, const unsigned short* __restrict__ Wl,
    float* __restrict__ C) {
    constexpr int K = 1024;
    // [buf3][kcell4][row128][8] each
    __shared__ __align__(16) unsigned short AsH[3 * 4096], AsL[3 * 4096],
                                            BsH[3 * 4096], BsL[3 * 4096];

    const int t = threadIdx.x;
    const int lane = t & 63;
    const int wave = t >> 6;               // 0..7
    const int l = lane & 15;
    const int quad = lane >> 4;
    const int wr = wave >> 1;              // 0..3
    const int wc = wave & 1;               // 0..1
    const int m0 = blockIdx.x * 128;   // m fastest -> XCD A-locality
    const int n0 = blockIdx.y * 128;

    // staging: thread t owns row (t&127), kcell (t>>7) of all 4 tensors.
    const int arow = t & 127, akc = t >> 7;
    const unsigned short* gah = Ah + (size_t)(m0 + arow) * K + akc * 8;
    const unsigned short* gal = Al + (size_t)(m0 + arow) * K + akc * 8;
    const unsigned short* gbh = Wh + (size_t)(n0 + arow) * K + akc * 8;
    const unsigned short* gbl = Wl + (size_t)(n0 + arow) * K + akc * 8;

    f32x4 acc[2][4];
#pragma unroll
    for (int i = 0; i < 2; i++)
#pragma unroll
        for (int j = 0; j < 4; j++) acc[i][j] = (f32x4){0.f, 0.f, 0.f, 0.f};

#define STAGE_OUT(koff, bo)                                                                \
    do {                                                                                   \
        __builtin_amdgcn_global_load_lds(                                                  \
            (const __attribute__((address_space(1))) unsigned int*)(gah + (koff)),         \
            (__attribute__((address_space(3))) unsigned int*)(AsH + (bo) + t * 8), 16, 0, 0); \
        __builtin_amdgcn_global_load_lds(                                                  \
            (const __attribute__((address_space(1))) unsigned int*)(gal + (koff)),         \
            (__attribute__((address_space(3))) unsigned int*)(AsL + (bo) + t * 8), 16, 0, 0); \
        __builtin_amdgcn_global_load_lds(                                                  \
            (const __attribute__((address_space(1))) unsigned int*)(gbh + (koff)),         \
            (__attribute__((address_space(3))) unsigned int*)(BsH + (bo) + t * 8), 16, 0, 0); \
        __builtin_amdgcn_global_load_lds(                                                  \
            (const __attribute__((address_space(1))) unsigned int*)(gbl + (koff)),         \
            (__attribute__((address_space(3))) unsigned int*)(BsL + (bo) + t * 8), 16, 0, 0); \
    } while (0)

    STAGE_OUT(0, 0);

    int bc = 0;   // it % 3
    for (int it = 0; it < 32; ++it) {
        if (it + 1 < 32) {
            int nb = bc + 1; if (nb == 3) nb = 0;     // (it+1) % 3
            STAGE_OUT((it + 1) * 32, nb * 4096);
            asm volatile("s_waitcnt vmcnt(4)" ::: "memory");   // own tile-it loads landed
        } else {
            asm volatile("s_waitcnt vmcnt(0)" ::: "memory");
        }
        __builtin_amdgcn_s_barrier();                          // all waves' tile-it loads landed
        const int bo = bc * 4096;
        bf16x8 ah[2], al[2], bh[4], bl[4];
#pragma unroll
        for (int i = 0; i < 2; i++) {
            int ra = bo + (quad * 128 + wr * 32 + i * 16 + l) * 8;
            ah[i] = *(const bf16x8*)&AsH[ra];
            al[i] = *(const bf16x8*)&AsL[ra];
        }
#pragma unroll
        for (int j = 0; j < 4; j++) {
            int rb = bo + (quad * 128 + wc * 64 + j * 16 + l) * 8;
            bh[j] = *(const bf16x8*)&BsH[rb];
            bl[j] = *(const bf16x8*)&BsL[rb];
        }
#pragma unroll
        for (int i = 0; i < 2; i++)
#pragma unroll
            for (int j = 0; j < 4; j++) {
                acc[i][j] = __builtin_amdgcn_mfma_f32_16x16x32_bf16(ah[i], bh[j], acc[i][j], 0, 0, 0);
                acc[i][j] = __builtin_amdgcn_mfma_f32_16x16x32_bf16(al[i], bh[j], acc[i][j], 0, 0, 0);
                acc[i][j] = __builtin_amdgcn_mfma_f32_16x16x32_bf16(ah[i], bl[j], acc[i][j], 0, 0, 0);
            }
        if (++bc == 3) bc = 0;
    }
#undef STAGE_OUT

#pragma unroll
    for (int i = 0; i < 2; i++)
#pragma unroll
        for (int j = 0; j < 4; j++)
#pragma unroll
            for (int r = 0; r < 4; r++) {
                int m = m0 + wr * 32 + i * 16 + quad * 4 + r;
                int n = n0 + wc * 64 + j * 16 + l;
                C[(size_t)m * Dc + n] = acc[i][j][r];
            }
}

// ---------------------------------------------------------------------------
extern "C" void kernel_launch(void* const* d_in, const int* in_sizes, int n_in,
                              void* d_out, int out_size, void* d_ws, size_t ws_size,
                              hipStream_t stream) {
    const float* x  = (const float*)d_in[0];
    const float* Wq = (const float*)d_in[1];
    const float* Wk = (const float*)d_in[2];
    const float* Wv = (const float*)d_in[3];
    const float* Wo = (const float*)d_in[4];
    float* out = (float*)d_out;

    unsigned short* usw = (unsigned short*)d_ws;
    const size_t M4 = (size_t)1 << 22;   // 4M elements
    unsigned short* whAll = usw;                 // 4 x 1M weights hi
    unsigned short* wlAll = usw + M4;            // lo (only Wo slot used)
    unsigned short* xh = usw + 2 * M4;           // x hi (later AOh)
    unsigned short* xl = usw + 3 * M4;           // later AOl
    unsigned short* Qh = usw + 4 * M4;
    unsigned short* Kh = usw + 5 * M4;
    unsigned short* Vh = usw + 6 * M4;
    float* ct = (float*)(usw + 7 * M4);
    float* st_ = ct + (size_t)Sc * 32;
    unsigned short* AOh = xh;   // x dead after QKV GEMM
    unsigned short* AOl = xl;

    // 1. RoPE table
    rope_table<<<dim3((Sc * 32) / 256), dim3(256), 0, stream>>>(ct, st_);
    // 2. convert x + weights to bf16 (Wo keeps hi/lo)
    split_xw<<<dim3(4096, 5), dim3(256), 0, stream>>>(x, Wq, Wk, Wv, Wo, xh, whAll, wlAll);
    // 3. QKV projections: 128x128 tiles, 8 waves/block (round-6 win, untouched)
    gemm_qkv<<<dim3(32, 8, 3), dim3(512), 0, stream>>>(
        xh, whAll, Qh, Kh, Vh, ct, st_);
    // 4. attention: 256q/block, 8 waves, 1 block/CU, counted-vmcnt triple-buffer
    attn10<<<dim3(256), dim3(512), 0, stream>>>(Qh, Kh, Vh, AOh, AOl);
    // 5. output projection: 8 waves, triple-buffer + counted vmcnt (no drain)
    gemm_out<<<dim3(32, 8), dim3(512), 0, stream>>>(
        AOh, AOl, whAll + 3 * (1 << 20), wlAll + 3 * (1 << 20), out);
}

// Round 8
// 229.432 us; speedup vs baseline: 1.0405x; 1.0405x over previous
//
#include <hip/hip_runtime.h>
#include <math.h>

// Problem constants
constexpr int Bc = 2;
constexpr int Sc = 2048;
constexpr int Dc = 1024;
constexpr int Hc = 16;
constexpr int HDc = 64;

// Q pre-scale: attention 1/sqrt(64) folded with log2(e) for exp2-domain softmax
constexpr float QSC = 0.125f * 1.4426950408889634f;

typedef __attribute__((ext_vector_type(8))) short bf16x8;
typedef __attribute__((ext_vector_type(4))) float f32x4;
typedef __attribute__((ext_vector_type(4))) unsigned short us4;
typedef __attribute__((ext_vector_type(2))) unsigned int u32x2;
typedef __attribute__((ext_vector_type(4))) unsigned int u32x4;

// fp32 -> bf16 round-to-nearest-even (returns low 16 bits)
__device__ __forceinline__ unsigned f2bf(float x) {
    unsigned u = __float_as_uint(x);
    return (u + 0x7FFFu + ((u >> 16) & 1u)) >> 16;
}

__device__ __forceinline__ void split2(float x, unsigned short& h, unsigned short& l) {
    unsigned hh = f2bf(x);
    h = (unsigned short)hh;
    l = (unsigned short)f2bf(x - __uint_as_float(hh << 16));
}

// gfx950 cross-lane half-swaps: a=vdst, b=src; both updated.
#if __has_builtin(__builtin_amdgcn_permlane32_swap)
__device__ __forceinline__ void plswap32(unsigned& a, unsigned& b) {
    u32x2 r = __builtin_amdgcn_permlane32_swap(a, b, false, false);
    a = r.x; b = r.y;
}
#else
__device__ __forceinline__ void plswap32(unsigned& a, unsigned& b) {
    asm volatile("v_permlane32_swap_b32 %0, %1" : "+v"(a), "+v"(b));
}
#endif
#if __has_builtin(__builtin_amdgcn_permlane16_swap)
__device__ __forceinline__ void plswap16(unsigned& a, unsigned& b) {
    u32x2 r = __builtin_amdgcn_permlane16_swap(a, b, false, false);
    a = r.x; b = r.y;
}
#else
__device__ __forceinline__ void plswap16(unsigned& a, unsigned& b) {
    asm volatile("v_permlane16_swap_b32 %0, %1" : "+v"(a), "+v"(b));
}
#endif

// exp2 of 4 S-values, packed (truncating) into two bf16-pair words:
// w0 = {bf16(s0) lo, bf16(s1) hi}, w1 = {bf16(s2) lo, bf16(s3) hi}
__device__ __forceinline__ void exppack(const f32x4& sv, unsigned& w0, unsigned& w1) {
    unsigned u0 = __float_as_uint(__builtin_amdgcn_exp2f(sv[0]));
    unsigned u1 = __float_as_uint(__builtin_amdgcn_exp2f(sv[1]));
    unsigned u2 = __float_as_uint(__builtin_amdgcn_exp2f(sv[2]));
    unsigned u3 = __float_as_uint(__builtin_amdgcn_exp2f(sv[3]));
    w0 = __builtin_amdgcn_perm(u1, u0, 0x07060302u);
    w1 = __builtin_amdgcn_perm(u3, u2, 0x07060302u);
}

// ---------------------------------------------------------------------------
// RoPE cos/sin table: [S][32] each, double precision angles.
// ---------------------------------------------------------------------------
__global__ void rope_table(float* __restrict__ ct, float* __restrict__ st_) {
    int id = blockIdx.x * 256 + threadIdx.x;
    int s = id >> 5;
    int i = id & 31;
    double invf = pow(10000.0, -(double)i / 32.0);
    double ang = (double)s * invf;
    ct[id] = (float)cos(ang);
    st_[id] = (float)sin(ang);
}

// ---------------------------------------------------------------------------
// Convert: x -> bf16 hi; Wq/Wk/Wv -> hi; Wo -> hi + lo.
// ---------------------------------------------------------------------------
__global__ void split_xw(const float* __restrict__ x,
                         const float* __restrict__ Wq, const float* __restrict__ Wk,
                         const float* __restrict__ Wv, const float* __restrict__ Wo,
                         unsigned short* __restrict__ xh,
                         unsigned short* __restrict__ whAll, unsigned short* __restrict__ wlAll) {
    int y = blockIdx.y;
    const float* src;
    unsigned short* h;
    unsigned short* l = nullptr;
    int n;
    if (y == 0) { src = x; h = xh; n = 1 << 22; }
    else {
        src = (y == 1) ? Wq : (y == 2) ? Wk : (y == 3) ? Wv : Wo;
        h = whAll + (size_t)(y - 1) * (1 << 20);
        if (y == 4) l = wlAll + (size_t)3 * (1 << 20);
        n = 1 << 20;
    }
    int i = (blockIdx.x * 256 + threadIdx.x) * 4;
    if (i >= n) return;
    float4 v = *(const float4*)(src + i);
    us4 hh;
    ((unsigned short*)&hh)[0] = (unsigned short)f2bf(v.x);
    ((unsigned short*)&hh)[1] = (unsigned short)f2bf(v.y);
    ((unsigned short*)&hh)[2] = (unsigned short)f2bf(v.z);
    ((unsigned short*)&hh)[3] = (unsigned short)f2bf(v.w);
    *(us4*)(h + i) = hh;
    if (l) {
        us4 ll;
        const float* vp = (const float*)&v;
#pragma unroll
        for (int e = 0; e < 4; e++) {
            unsigned short hi = ((unsigned short*)&hh)[e];
            ((unsigned short*)&ll)[e] =
                (unsigned short)f2bf(vp[e] - __uint_as_float((unsigned)hi << 16));
        }
        *(us4*)(l + i) = ll;
    }
}

// ---------------------------------------------------------------------------
// QKV GEMM, bf16 1-product, 128x128 tile, BK=32, dbuf, 8 waves (512 thr,
// per-wave 32x64 subtile) — round-6 proven: 60us, occ 58%. UNTOUCHED.
// Epilogues: z=0 Q (RoPE+QSC row-major), z=1 K (RoPE, [T][kb][tok][8] cells),
//            z=2 V (V^T cells [T][kk(2)][qd(4)][d(64)][tok8] — native K=32
//                   A-operand layout for attention PV)
// ---------------------------------------------------------------------------
__global__ __launch_bounds__(512, 4) void gemm_qkv(
    const unsigned short* __restrict__ Ah,
    const unsigned short* __restrict__ whAll,
    unsigned short* __restrict__ Qh,
    unsigned short* __restrict__ Kh,
    unsigned short* __restrict__ Vh,
    const float* __restrict__ ct, const float* __restrict__ st_) {
    constexpr int K = 1024;
    // [buf2][kcell4][row128][8]
    __shared__ __align__(16) unsigned short As[2 * 4096], Bs[2 * 4096];

    const int z = blockIdx.z;
    const unsigned short* Wh = whAll + (size_t)z * (1 << 20);

    const int t = threadIdx.x;
    const int lane = t & 63;
    const int wave = t >> 6;               // 0..7
    const int l = lane & 15;
    const int quad = lane >> 4;
    const int wr = wave >> 1;              // 0..3: 32-row strip
    const int wc = wave & 1;               // 0..1: 64-col strip (= head)
    const int m0 = blockIdx.x * 128;
    const int n0 = blockIdx.y * 128;

    // staging: thread t owns row (t&127), kcell (t>>7) of both A and B.
    const int arow = t & 127, akc = t >> 7;
    const unsigned short* gA = Ah + (size_t)(m0 + arow) * K + akc * 8;
    const unsigned short* gB = Wh + (size_t)(n0 + arow) * K + akc * 8;

    f32x4 acc[2][4];
#pragma unroll
    for (int i = 0; i < 2; i++)
#pragma unroll
        for (int j = 0; j < 4; j++) acc[i][j] = (f32x4){0.f, 0.f, 0.f, 0.f};

    __builtin_amdgcn_global_load_lds(
        (const __attribute__((address_space(1))) unsigned int*)gA,
        (__attribute__((address_space(3))) unsigned int*)(As + t * 8), 16, 0, 0);
    __builtin_amdgcn_global_load_lds(
        (const __attribute__((address_space(1))) unsigned int*)gB,
        (__attribute__((address_space(3))) unsigned int*)(Bs + t * 8), 16, 0, 0);

    for (int it = 0; it < 32; ++it) {
        __syncthreads();
        if (it + 1 < 32) {
            const int koff = (it + 1) * 32;
            const int bo = ((it + 1) & 1) * 4096;
            __builtin_amdgcn_global_load_lds(
                (const __attribute__((address_space(1))) unsigned int*)(gA + koff),
                (__attribute__((address_space(3))) unsigned int*)(As + bo + t * 8), 16, 0, 0);
            __builtin_amdgcn_global_load_lds(
                (const __attribute__((address_space(1))) unsigned int*)(gB + koff),
                (__attribute__((address_space(3))) unsigned int*)(Bs + bo + t * 8), 16, 0, 0);
        }
        const unsigned short* a = As + (it & 1) * 4096;
        const unsigned short* bb = Bs + (it & 1) * 4096;
        bf16x8 ah[2], bh[4];
#pragma unroll
        for (int i = 0; i < 2; i++)
            ah[i] = *(const bf16x8*)&a[(quad * 128 + wr * 32 + i * 16 + l) * 8];
#pragma unroll
        for (int j = 0; j < 4; j++)
            bh[j] = *(const bf16x8*)&bb[(quad * 128 + wc * 64 + j * 16 + l) * 8];
#pragma unroll
        for (int i = 0; i < 2; i++)
#pragma unroll
            for (int j = 0; j < 4; j++)
                acc[i][j] = __builtin_amdgcn_mfma_f32_16x16x32_bf16(ah[i], bh[j], acc[i][j], 0, 0, 0);
    }

    // ---- fused epilogue ----
    const int hcol = blockIdx.y * 2 + wc;   // head index 0..15
    if (z == 2) {
        // V^T cells, K=32 A-operand layout:
        //   off = ((kk*4 + qd)*64 + d)*8 + tj, tok64 = kk*32 + qd*8 + tj
        // acc[i][jj][r]: tok64 = ii*16 + quad*4 + r with ii = (2*wr+i)&3
#pragma unroll
        for (int i = 0; i < 2; i++) {
            int m_base = m0 + wr * 32 + i * 16 + quad * 4;
            int bbk = m_base >> 11;
            int T = (m_base & (Sc - 1)) >> 6;
            int ii = (2 * wr + i) & 3;
            int kk = ii >> 1;
            int qd = ((ii & 1) << 1) | (quad >> 1);
            int tj = (quad & 1) * 4;
            size_t tilebase = (((size_t)(bbk * Hc + hcol)) * 32 + T) * 4096;
#pragma unroll
            for (int jj = 0; jj < 4; jj++) {
                int d = jj * 16 + l;
                size_t off = tilebase + (size_t)(((kk * 4 + qd) * 64 + d) * 8 + tj);
                us4 v4;
#pragma unroll
                for (int r = 0; r < 4; r++)
                    ((unsigned short*)&v4)[r] = (unsigned short)f2bf(acc[i][jj][r]);
                *(us4*)(Vh + off) = v4;
            }
        }
    } else {
#pragma unroll
        for (int i = 0; i < 2; i++)
#pragma unroll
            for (int r = 0; r < 4; r++) {
                int m = m0 + wr * 32 + i * 16 + quad * 4 + r;
                int bbk = m >> 11, s = m & (Sc - 1);
#pragma unroll
                for (int jp = 0; jp < 2; jp++) {
                    int d = jp * 16 + l;                       // 0..31
                    float cs = ct[s * 32 + d];
                    float sn = st_[s * 32 + d];
                    float x0 = acc[i][jp][r];
                    float x1 = acc[i][jp + 2][r];
                    float y0 = x0 * cs - x1 * sn;
                    float y1 = x1 * cs + x0 * sn;
                    if (z == 0) {
                        size_t rowb = (((size_t)(bbk * Hc + hcol)) * Sc + s) * HDc;
                        Qh[rowb + d]      = (unsigned short)f2bf(y0 * QSC);
                        Qh[rowb + d + 32] = (unsigned short)f2bf(y1 * QSC);
                    } else {
                        int T = s >> 6, tok = s & 63;
                        size_t tb = (((size_t)(bbk * Hc + hcol)) * 32 + T) * 8;
                        size_t off0 = ((tb + (d >> 3)) * 64 + tok) * 8 + (d & 7);
                        size_t off1 = ((tb + (d >> 3) + 4) * 64 + tok) * 8 + (d & 7);
                        Kh[off0] = (unsigned short)f2bf(y0);
                        Kh[off1] = (unsigned short)f2bf(y1);
                    }
                }
            }
    }
}

// ---------------------------------------------------------------------------
// MFMA flash attention v10: all-K=32 MFMA, 256 q/block (8 waves x 2 bands),
// grid 256 = 1 block/CU. Triple-buffered K/V + per-wave counted vmcnt(2)
// before raw s_barrier. Round-7: left the top-5 (<68us). UNTOUCHED.
// ---------------------------------------------------------------------------
__global__ __launch_bounds__(512) void attn10(
    const unsigned short* __restrict__ Qh,
    const unsigned short* __restrict__ Kh,
    const unsigned short* __restrict__ Vh,
    unsigned short* __restrict__ AOh, unsigned short* __restrict__ AOl) {
    __shared__ __align__(16) unsigned short KsH[3 * 4096], VtH[3 * 4096];

    const int t = threadIdx.x;
    const int lane = t & 63;
    const int wave = t >> 6;               // 0..7
    const int l = lane & 15;
    const int quad = lane >> 4;
    const int id = blockIdx.x;             // 0..255
    const int bh = (id & 7) * 4 + (id >> 6);   // XCD-clustered (4 bh / XCD slot)
    const int qt = (id >> 3) & 7;
    const int q0 = qt * 256;
    const int b = bh >> 4;
    const int hh = bh & 15;

    const bf16x8 ONES8 = {(short)0x3F80, (short)0x3F80, (short)0x3F80, (short)0x3F80,
                          (short)0x3F80, (short)0x3F80, (short)0x3F80, (short)0x3F80};

    // Q fragments (B operand: n=q=lane&15, k=d=quad*8+j); band bnd -> rows
    // q0 + wave*32 + bnd*16 + l
    bf16x8 qf[2][2];
#pragma unroll
    for (int bnd = 0; bnd < 2; bnd++) {
        size_t rowb = ((size_t)bh * Sc + q0 + wave * 32 + bnd * 16 + l) * HDc;
#pragma unroll
        for (int ks = 0; ks < 2; ks++)
            qf[bnd][ks] = *(const bf16x8*)(Qh + rowb + ks * 32 + quad * 8);
    }

    f32x4 o[2][4], lac[2];
#pragma unroll
    for (int bnd = 0; bnd < 2; bnd++) {
        lac[bnd] = (f32x4){0.f, 0.f, 0.f, 0.f};
#pragma unroll
        for (int i = 0; i < 4; i++) o[bnd][i] = (f32x4){0.f, 0.f, 0.f, 0.f};
    }

    // staging: 16 chunks of 512 elems per kt (K: 0-7, V: 8-15); wave w owns
    // chunks w*2, w*2+1 (waves 0-3 -> K, waves 4-7 -> V). LDS dst uniform.
    const int tensor = wave >> 2;          // 0 = K, 1 = V
    const int coff0 = (wave * 2) & 7;      // 0,2,4,6
    unsigned short* larr = tensor ? VtH : KsH;
    const unsigned short* gT =
        (tensor ? Vh : Kh) + (size_t)bh * Sc * HDc + coff0 * 512 + lane * 8;

    // prologue: kt=0 into buffer 0
#pragma unroll
    for (int q = 0; q < 2; q++)
        __builtin_amdgcn_global_load_lds(
            (const __attribute__((address_space(1))) unsigned int*)(gT + q * 512),
            (__attribute__((address_space(3))) unsigned int*)(larr + coff0 * 512 + q * 512),
            16, 0, 0);

    int bc = 0;   // kt % 3
    for (int kt = 0; kt < 32; kt++) {
        if (kt + 1 < 32) {
            int nb = bc + 1; if (nb == 3) nb = 0;     // (kt+1) % 3
            const unsigned short* g = gT + (size_t)(kt + 1) * 4096;
            unsigned short* dst = larr + nb * 4096 + coff0 * 512;
#pragma unroll
            for (int q = 0; q < 2; q++)
                __builtin_amdgcn_global_load_lds(
                    (const __attribute__((address_space(1))) unsigned int*)(g + q * 512),
                    (__attribute__((address_space(3))) unsigned int*)(dst + q * 512),
                    16, 0, 0);
            asm volatile("s_waitcnt vmcnt(2)" ::: "memory");   // own kt-loads landed
        } else {
            asm volatile("s_waitcnt vmcnt(0)" ::: "memory");
        }
        __builtin_amdgcn_s_barrier();                          // all waves' kt-loads landed
        const unsigned short* Kbuf = KsH + bc * 4096;
        const unsigned short* Vbuf = VtH + bc * 4096;

        // ---- S^T = K @ Q^T: A=K frag (m=tok), B=Q frag (n=q) ----
        f32x4 s[2][4];
#pragma unroll
        for (int bnd = 0; bnd < 2; bnd++)
#pragma unroll
            for (int tt = 0; tt < 4; tt++) s[bnd][tt] = (f32x4){0.f, 0.f, 0.f, 0.f};
        __builtin_amdgcn_s_setprio(1);
#pragma unroll
        for (int ks = 0; ks < 2; ks++)
#pragma unroll
            for (int tt = 0; tt < 4; tt++) {
                bf16x8 kf = *(const bf16x8*)&Kbuf[((ks * 4 + quad) * 64 + tt * 16 + l) * 8];
                s[0][tt] = __builtin_amdgcn_mfma_f32_16x16x32_bf16(kf, qf[0][ks], s[0][tt], 0, 0, 0);
                s[1][tt] = __builtin_amdgcn_mfma_f32_16x16x32_bf16(kf, qf[1][ks], s[1][tt], 0, 0, 0);
            }
        __builtin_amdgcn_s_setprio(0);

        // ---- P^T = exp2(S^T), packed + permlane-transposed into K=32
        //      B-operand fragments (tokens quad*8+j contiguous per lane) ----
        bf16x8 pf[2][2];
#pragma unroll
        for (int bnd = 0; bnd < 2; bnd++)
#pragma unroll
            for (int ttp = 0; ttp < 2; ttp++) {
                unsigned A0, A1, B0, B1;
                exppack(s[bnd][2 * ttp], A0, A1);       // tokens ttp*32 + quad*4 + {0..3}
                exppack(s[bnd][2 * ttp + 1], B0, B1);   // tokens ttp*32 + 16 + quad*4 + {0..3}
                plswap32(A0, B0);
                plswap16(A0, B0);   // A0 -> frag word0, B0 -> frag word2
                plswap32(A1, B1);
                plswap16(A1, B1);   // A1 -> frag word1, B1 -> frag word3
                u32x4 fw = {A0, A1, B0, B1};
                bf16x8 p8 = __builtin_bit_cast(bf16x8, fw);
                pf[bnd][ttp] = p8;
                lac[bnd] = __builtin_amdgcn_mfma_f32_16x16x32_bf16(ONES8, p8, lac[bnd], 0, 0, 0);
            }

        // ---- O^T += V^T @ P^T (K=32; V frags shared across bands) ----
        __builtin_amdgcn_s_setprio(1);
#pragma unroll
        for (int kk = 0; kk < 2; kk++)
#pragma unroll
            for (int dd = 0; dd < 4; dd++) {
                bf16x8 vf = *(const bf16x8*)
                    &Vbuf[(size_t)((kk * 4 + quad) * 64 + dd * 16 + l) * 8];
                o[0][dd] = __builtin_amdgcn_mfma_f32_16x16x32_bf16(vf, pf[0][kk], o[0][dd], 0, 0, 0);
                o[1][dd] = __builtin_amdgcn_mfma_f32_16x16x32_bf16(vf, pf[1][kk], o[1][dd], 0, 0, 0);
            }
        __builtin_amdgcn_s_setprio(0);
        if (++bc == 3) bc = 0;
    }

    // ---- epilogue: O^T frag: col q = lane&15, row d = dd*16 + quad*4 + r ----
#pragma unroll
    for (int bnd = 0; bnd < 2; bnd++) {
        float inv = 1.f / lac[bnd][0];   // all 4 regs equal (ONES-A rows identical)
        int q = q0 + wave * 32 + bnd * 16 + l;
        size_t rowb = ((size_t)b * Sc + q) * Dc + hh * HDc + quad * 4;
#pragma unroll
        for (int dd = 0; dd < 4; dd++) {
            us4 h4, l4;
#pragma unroll
            for (int r = 0; r < 4; r++)
                split2(o[bnd][dd][r] * inv,
                       ((unsigned short*)&h4)[r], ((unsigned short*)&l4)[r]);
            *(us4*)(AOh + rowb + dd * 16) = h4;
            *(us4*)(AOl + rowb + dd * 16) = l4;
        }
    }
}

// ---------------------------------------------------------------------------
// Output projection GEMM (MFMA split-bf16 3-product, dbuf, round-6 loop),
// 128x128 tile, 8 waves, SPLIT-K=2 via separate partials (NO atomics):
// z=0 -> out, z=1 -> P1. Grid 512 = 2 blocks/CU -> per-CU DMA rate doubles.
// ---------------------------------------------------------------------------
__global__ __launch_bounds__(512, 4) void gemm_out(
    const unsigned short* __restrict__ Ah, const unsigned short* __restrict__ Al,
    const unsigned short* __restrict__ Wh, const unsigned short* __restrict__ Wl,
    float* __restrict__ C0, float* __restrict__ C1) {
    constexpr int K = 1024;
    // [buf2][kcell4][row128][8] each
    __shared__ __align__(16) unsigned short AsH[2 * 4096], AsL[2 * 4096],
                                            BsH[2 * 4096], BsL[2 * 4096];

    const int t = threadIdx.x;
    const int lane = t & 63;
    const int wave = t >> 6;               // 0..7
    const int l = lane & 15;
    const int quad = lane >> 4;
    const int wr = wave >> 1;              // 0..3
    const int wc = wave & 1;               // 0..1
    const int m0 = blockIdx.x * 128;   // m fastest -> XCD A-locality
    const int n0 = blockIdx.y * 128;
    const int k0 = blockIdx.z * 512;   // split-K half
    float* __restrict__ C = blockIdx.z ? C1 : C0;

    // staging: thread t owns row (t&127), kcell (t>>7) of all 4 tensors.
    const int arow = t & 127, akc = t >> 7;
    const unsigned short* gah = Ah + (size_t)(m0 + arow) * K + k0 + akc * 8;
    const unsigned short* gal = Al + (size_t)(m0 + arow) * K + k0 + akc * 8;
    const unsigned short* gbh = Wh + (size_t)(n0 + arow) * K + k0 + akc * 8;
    const unsigned short* gbl = Wl + (size_t)(n0 + arow) * K + k0 + akc * 8;

    f32x4 acc[2][4];
#pragma unroll
    for (int i = 0; i < 2; i++)
#pragma unroll
        for (int j = 0; j < 4; j++) acc[i][j] = (f32x4){0.f, 0.f, 0.f, 0.f};

#define STAGE_OUT(koff, bo)                                                                \
    do {                                                                                   \
        __builtin_amdgcn_global_load_lds(                                                  \
            (const __attribute__((address_space(1))) unsigned int*)(gah + (koff)),         \
            (__attribute__((address_space(3))) unsigned int*)(AsH + (bo) + t * 8), 16, 0, 0); \
        __builtin_amdgcn_global_load_lds(                                                  \
            (const __attribute__((address_space(1))) unsigned int*)(gal + (koff)),         \
            (__attribute__((address_space(3))) unsigned int*)(AsL + (bo) + t * 8), 16, 0, 0); \
        __builtin_amdgcn_global_load_lds(                                                  \
            (const __attribute__((address_space(1))) unsigned int*)(gbh + (koff)),         \
            (__attribute__((address_space(3))) unsigned int*)(BsH + (bo) + t * 8), 16, 0, 0); \
        __builtin_amdgcn_global_load_lds(                                                  \
            (const __attribute__((address_space(1))) unsigned int*)(gbl + (koff)),         \
            (__attribute__((address_space(3))) unsigned int*)(BsL + (bo) + t * 8), 16, 0, 0); \
    } while (0)

    STAGE_OUT(0, 0);

    for (int it = 0; it < 16; ++it) {
        __syncthreads();
        if (it + 1 < 16) STAGE_OUT((it + 1) * 32, ((it + 1) & 1) * 4096);
        const int bo = (it & 1) * 4096;
        bf16x8 ah[2], al[2], bh[4], bl[4];
#pragma unroll
        for (int i = 0; i < 2; i++) {
            int ra = bo + (quad * 128 + wr * 32 + i * 16 + l) * 8;
            ah[i] = *(const bf16x8*)&AsH[ra];
            al[i] = *(const bf16x8*)&AsL[ra];
        }
#pragma unroll
        for (int j = 0; j < 4; j++) {
            int rb = bo + (quad * 128 + wc * 64 + j * 16 + l) * 8;
            bh[j] = *(const bf16x8*)&BsH[rb];
            bl[j] = *(const bf16x8*)&BsL[rb];
        }
#pragma unroll
        for (int i = 0; i < 2; i++)
#pragma unroll
            for (int j = 0; j < 4; j++) {
                acc[i][j] = __builtin_amdgcn_mfma_f32_16x16x32_bf16(ah[i], bh[j], acc[i][j], 0, 0, 0);
                acc[i][j] = __builtin_amdgcn_mfma_f32_16x16x32_bf16(al[i], bh[j], acc[i][j], 0, 0, 0);
                acc[i][j] = __builtin_amdgcn_mfma_f32_16x16x32_bf16(ah[i], bl[j], acc[i][j], 0, 0, 0);
            }
    }
#undef STAGE_OUT

#pragma unroll
    for (int i = 0; i < 2; i++)
#pragma unroll
        for (int j = 0; j < 4; j++)
#pragma unroll
            for (int r = 0; r < 4; r++) {
                int m = m0 + wr * 32 + i * 16 + quad * 4 + r;
                int n = n0 + wc * 64 + j * 16 + l;
                C[(size_t)m * Dc + n] = acc[i][j][r];
            }
}

// ---------------------------------------------------------------------------
// Split-K combine: out += P1 (float4 vectorized).
// ---------------------------------------------------------------------------
__global__ void add_partial(float* __restrict__ out, const float* __restrict__ p1) {
    int i = (blockIdx.x * 256 + threadIdx.x) * 4;
    float4 a = *(const float4*)(out + i);
    float4 b = *(const float4*)(p1 + i);
    a.x += b.x; a.y += b.y; a.z += b.z; a.w += b.w;
    *(float4*)(out + i) = a;
}

// ---------------------------------------------------------------------------
extern "C" void kernel_launch(void* const* d_in, const int* in_sizes, int n_in,
                              void* d_out, int out_size, void* d_ws, size_t ws_size,
                              hipStream_t stream) {
    const float* x  = (const float*)d_in[0];
    const float* Wq = (const float*)d_in[1];
    const float* Wk = (const float*)d_in[2];
    const float* Wv = (const float*)d_in[3];
    const float* Wo = (const float*)d_in[4];
    float* out = (float*)d_out;

    unsigned short* usw = (unsigned short*)d_ws;
    const size_t M4 = (size_t)1 << 22;   // 4M elements
    unsigned short* whAll = usw;                 // 4 x 1M weights hi
    unsigned short* wlAll = usw + M4;            // lo (only Wo slot used)
    unsigned short* xh = usw + 2 * M4;           // x hi (later AOh)
    unsigned short* xl = usw + 3 * M4;           // later AOl
    unsigned short* Qh = usw + 4 * M4;
    unsigned short* Kh = usw + 5 * M4;
    unsigned short* Vh = usw + 6 * M4;
    float* ct = (float*)(usw + 7 * M4);
    float* st_ = ct + (size_t)Sc * 32;
    unsigned short* AOh = xh;   // x dead after QKV GEMM
    unsigned short* AOl = xl;
    // split-K partial: 16 MB fp32 reusing Qh+Kh slots (dead after attn)
    float* P1 = (float*)Qh;

    // 1. RoPE table
    rope_table<<<dim3((Sc * 32) / 256), dim3(256), 0, stream>>>(ct, st_);
    // 2. convert x + weights to bf16 (Wo keeps hi/lo)
    split_xw<<<dim3(4096, 5), dim3(256), 0, stream>>>(x, Wq, Wk, Wv, Wo, xh, whAll, wlAll);
    // 3. QKV projections: 128x128 tiles, 8 waves/block (round-6 win, untouched)
    gemm_qkv<<<dim3(32, 8, 3), dim3(512), 0, stream>>>(
        xh, whAll, Qh, Kh, Vh, ct, st_);
    // 4. attention: 256q/block, 8 waves, 1 block/CU, counted-vmcnt triple-buffer
    attn10<<<dim3(256), dim3(512), 0, stream>>>(Qh, Kh, Vh, AOh, AOl);
    // 5. output projection: split-K=2 partials (z=0 -> out, z=1 -> P1)
    gemm_out<<<dim3(32, 8, 2), dim3(512), 0, stream>>>(
        AOh, AOl, whAll + 3 * (1 << 20), wlAll + 3 * (1 << 20), out, P1);
    // 6. combine partials
    add_partial<<<dim3(4096), dim3(256), 0, stream>>>(out, P1);
}